// Round 2
// baseline (745.005 us; speedup 1.0000x reference)
//
#include <hip/hip_runtime.h>

#define P_PTS 10000
#define NPTS 100
#define TB 8   // batches per block in MLP kernel

// ---------------- Kernel 1: foveate ----------------
// One 256-thread block per batch. Scan points in index order, collect first
// min(count,100) in-box points (stable order), early-exit once 100 found.
// Total count is only observable in the output when it is <100, in which
// case the scan runs to exhaustion anyway — so early exit is exact.
__global__ __launch_bounds__(256) void foveate_kernel(
    const float* __restrict__ x,   // (B,3,P)
    const float* __restrict__ l,   // (B,3)
    float* __restrict__ phi)       // (B,300) = (B,3,100)
{
    const int b   = blockIdx.x;
    const int tid = threadIdx.x;
    const int wid = tid >> 6, lane = tid & 63;

    __shared__ float s_phi[3][NPTS];
    __shared__ int s_wcnt[4];

    const float lx = l[b * 3 + 0];
    const float ly = l[b * 3 + 1];
    const float lz = l[b * 3 + 2];
    // identical arithmetic to the reference (l - 0.25f / l + 0.25f in fp32)
    const float lox = lx - 0.25f, hix = lx + 0.25f;
    const float loy = ly - 0.25f, hiy = ly + 0.25f;
    const float loz = lz - 0.25f, hiz = lz + 0.25f;

    const float* xb = x + (size_t)b * 3 * P_PTS;

    int cnt = 0;  // block-uniform running inside count
    for (int base = 0; base < P_PTS; base += 256) {
        const int p = base + tid;
        bool inside = false;
        float x0 = 0.f, x1 = 0.f, x2 = 0.f;
        if (p < P_PTS) {
            x0 = xb[p];
            x1 = xb[P_PTS + p];
            x2 = xb[2 * P_PTS + p];
            inside = (x0 >= lox) && (x0 <= hix) &&
                     (x1 >= loy) && (x1 <= hiy) &&
                     (x2 >= loz) && (x2 <= hiz);
        }
        const unsigned long long m = __ballot(inside);
        if (lane == 0) s_wcnt[wid] = __popcll(m);
        __syncthreads();
        int prefix = 0, total = 0;
        #pragma unroll
        for (int w = 0; w < 4; ++w) {
            const int c = s_wcnt[w];
            total += c;
            if (w < wid) prefix += c;
        }
        const int mypos = cnt + prefix +
                          __popcll(m & ((1ull << lane) - 1ull));
        if (inside && mypos < NPTS) {
            s_phi[0][mypos] = x0;
            s_phi[1][mypos] = x1;
            s_phi[2][mypos] = x2;
        }
        cnt += total;           // identical on all threads (uniform)
        __syncthreads();        // protect s_wcnt reuse + s_phi visibility
        if (cnt >= NPTS) break; // uniform exit
    }

    const int n = (cnt < NPTS) ? cnt : NPTS;
    if (n == 0) {
        for (int j = tid; j < 3 * NPTS; j += 256)
            ((float*)s_phi)[j] = 0.0f;
    } else if (n < NPTS) {
        // wrap: idx[j] = inside_idx[j % n]; reads [0,n), writes [n,NPTS) — disjoint
        for (int j = n + tid; j < NPTS; j += 256) {
            const int src = j % n;
            s_phi[0][j] = s_phi[0][src];
            s_phi[1][j] = s_phi[1][src];
            s_phi[2][j] = s_phi[2][src];
        }
    }
    __syncthreads();

    for (int j = tid; j < 3 * NPTS; j += 256)
        phi[(size_t)b * 300 + j] = ((const float*)s_phi)[j];
}

// ---------------- Kernel 2: fused MLP ----------------
// TB=8 batches per 256-thread block. fp32 throughout.
__global__ __launch_bounds__(256) void mlp_kernel(
    const float* __restrict__ phi,  // (B,300)
    const float* __restrict__ l,    // (B,3)
    const float* __restrict__ W1,   // (128,300)
    const float* __restrict__ b1,   // (128)
    const float* __restrict__ W2,   // (128,3)
    const float* __restrict__ b2,   // (128)
    const float* __restrict__ W3,   // (256,128)
    const float* __restrict__ b3,   // (256)
    const float* __restrict__ W4,   // (256,128)
    const float* __restrict__ b4,   // (256)
    float* __restrict__ out)        // (B,256)
{
    __shared__ float s_phi[TB][300];
    __shared__ float s_h1[TB][128];
    __shared__ float s_lo[TB][128];

    const int tid = threadIdx.x;
    const int b0  = blockIdx.x * TB;

    // stage phi tile (coalesced)
    for (int f = tid; f < TB * 300; f += 256)
        ((float*)s_phi)[f] = phi[(size_t)b0 * 300 + f];
    __syncthreads();

    const int b  = tid >> 5;   // 0..7 : batch within tile
    const int k0 = tid & 31;   // 0..31

    const float la = l[(b0 + b) * 3 + 0];
    const float lb = l[(b0 + b) * 3 + 1];
    const float lc = l[(b0 + b) * 3 + 2];

    // h1 = relu(phi @ W1^T + b1): each thread does k = k0 + 32j, j<4
    float acc[4];
    #pragma unroll
    for (int j = 0; j < 4; ++j)
        acc[j] = b1[k0 + 32 * j];
    for (int i = 0; i < 300; i += 4) {
        const float4 ph = *(const float4*)&s_phi[b][i];  // 8-way broadcast per b, stride 300 → conflict-free
        #pragma unroll
        for (int j = 0; j < 4; ++j) {
            const int k = k0 + 32 * j;
            const float4 w = *(const float4*)(W1 + k * 300 + i);  // 1200B row stride, 16B aligned
            acc[j] += ph.x * w.x + ph.y * w.y + ph.z * w.z + ph.w * w.w;
        }
    }
    #pragma unroll
    for (int j = 0; j < 4; ++j) {
        const int k = k0 + 32 * j;
        s_h1[b][k] = fmaxf(acc[j], 0.0f);
        const float lo = b2[k] + la * W2[k * 3 + 0] +
                                 lb * W2[k * 3 + 1] +
                                 lc * W2[k * 3 + 2];
        s_lo[b][k] = fmaxf(lo, 0.0f);
    }
    __syncthreads();

    // out = relu(h1 @ W3^T + b3 + l_out @ W4^T + b4): m = k0 + 32j, j<8
    float acc2[8];
    #pragma unroll
    for (int j = 0; j < 8; ++j) {
        const int m = k0 + 32 * j;
        acc2[j] = b3[m] + b4[m];
    }
    for (int k = 0; k < 128; k += 4) {
        const float4 h  = *(const float4*)&s_h1[b][k];
        const float4 lo = *(const float4*)&s_lo[b][k];
        #pragma unroll
        for (int j = 0; j < 8; ++j) {
            const int m = k0 + 32 * j;
            const float4 w3 = *(const float4*)(W3 + m * 128 + k);  // 512B row stride
            const float4 w4 = *(const float4*)(W4 + m * 128 + k);
            acc2[j] += h.x  * w3.x + h.y  * w3.y + h.z  * w3.z + h.w  * w3.w +
                       lo.x * w4.x + lo.y * w4.y + lo.z * w4.z + lo.w * w4.w;
        }
    }
    #pragma unroll
    for (int j = 0; j < 8; ++j) {
        const int m = k0 + 32 * j;
        out[(size_t)(b0 + b) * 256 + m] = fmaxf(acc2[j], 0.0f);
    }
}

extern "C" void kernel_launch(void* const* d_in, const int* in_sizes, int n_in,
                              void* d_out, int out_size, void* d_ws, size_t ws_size,
                              hipStream_t stream) {
    const float* x  = (const float*)d_in[0];
    const float* l  = (const float*)d_in[1];
    const float* W1 = (const float*)d_in[2];
    const float* b1 = (const float*)d_in[3];
    const float* W2 = (const float*)d_in[4];
    const float* b2 = (const float*)d_in[5];
    const float* W3 = (const float*)d_in[6];
    const float* b3 = (const float*)d_in[7];
    const float* W4 = (const float*)d_in[8];
    const float* b4 = (const float*)d_in[9];
    float* out = (float*)d_out;
    float* phi = (float*)d_ws;  // (B,300) fp32 staging: 4096*300*4 = 4.9 MB

    const int B = in_sizes[1] / 3;  // 4096

    foveate_kernel<<<B, 256, 0, stream>>>(x, l, phi);
    mlp_kernel<<<B / TB, 256, 0, stream>>>(phi, l, W1, b1, W2, b2,
                                           W3, b3, W4, b4, out);
}

// Round 3
// 683.622 us; speedup vs baseline: 1.0898x; 1.0898x over previous
//
#include <hip/hip_runtime.h>

#define NPTS 100          // points kept per cloud
#define P_F4 2500         // 10000 points / 4 per float4

// ---------------- Kernel F: foveate (one wave per batch) ----------------
// Wave w of each block handles batch b = blockIdx*4 + w. float4 loads cover
// 256 points per wave-iteration; stable compaction via 4 ballots; uniform
// early-exit once 100 in-box points are found (total count is only
// observable when <100, in which case the scan exhausts anyway).
// Output: phiT[i][b] (feature-major) so the MLP reads are coalesced.
__global__ __launch_bounds__(256) void foveate_kernel(
    const float* __restrict__ x,     // (B,3,10000)
    const float* __restrict__ l,     // (B,3)
    float* __restrict__ phiT,        // (300,B)
    int B)
{
    const int tid  = threadIdx.x;
    const int wv   = tid >> 6;
    const int lane = tid & 63;
    const int b    = blockIdx.x * 4 + wv;

    __shared__ float s_phi[4][300];  // per-wave phi buffer: [axis*100 + j]

    const float lx = l[b * 3 + 0];
    const float ly = l[b * 3 + 1];
    const float lz = l[b * 3 + 2];
    const float lox = lx - 0.25f, hix = lx + 0.25f;  // same fp32 arithmetic as ref
    const float loy = ly - 0.25f, hiy = ly + 0.25f;
    const float loz = lz - 0.25f, hiz = lz + 0.25f;

    const float4* xr = (const float4*)(x + (size_t)b * 30000);  // rows: 0 / 2500 / 5000 f4

    // prefetch iteration 0
    int fc = (lane < P_F4) ? lane : (P_F4 - 1);
    float4 a = xr[fc], c = xr[P_F4 + fc], d = xr[2 * P_F4 + fc];

    int cnt = 0;  // wave-uniform running in-box count
    for (int base = 0; base < P_F4; base += 64) {
        const int  f0 = base + lane;
        const bool v  = (f0 < P_F4);
        const float4 ca = a, cc = c, cd = d;
        if (base + 64 < P_F4) {  // uniform: prefetch next iteration
            int nf = base + 64 + lane;
            int nfc = (nf < P_F4) ? nf : (P_F4 - 1);
            a = xr[nfc]; c = xr[P_F4 + nfc]; d = xr[2 * P_F4 + nfc];
        }
        const bool in0 = v && ca.x >= lox && ca.x <= hix && cc.x >= loy && cc.x <= hiy && cd.x >= loz && cd.x <= hiz;
        const bool in1 = v && ca.y >= lox && ca.y <= hix && cc.y >= loy && cc.y <= hiy && cd.y >= loz && cd.y <= hiz;
        const bool in2 = v && ca.z >= lox && ca.z <= hix && cc.z >= loy && cc.z <= hiy && cd.z >= loz && cd.z <= hiz;
        const bool in3 = v && ca.w >= lox && ca.w <= hix && cc.w >= loy && cc.w <= hiy && cd.w >= loz && cd.w <= hiz;

        const unsigned long long m0 = __ballot(in0);
        const unsigned long long m1 = __ballot(in1);
        const unsigned long long m2 = __ballot(in2);
        const unsigned long long m3 = __ballot(in3);
        const unsigned long long below = (1ull << lane) - 1ull;

        // point order is lane-major (lane L owns points 4L..4L+3), so all of
        // lanes <L precede lane L's points, and sub-index order within lane.
        int pos = cnt + __popcll(m0 & below) + __popcll(m1 & below) +
                        __popcll(m2 & below) + __popcll(m3 & below);
        if (in0) { if (pos < NPTS) { s_phi[wv][pos] = ca.x; s_phi[wv][NPTS + pos] = cc.x; s_phi[wv][2 * NPTS + pos] = cd.x; } ++pos; }
        if (in1) { if (pos < NPTS) { s_phi[wv][pos] = ca.y; s_phi[wv][NPTS + pos] = cc.y; s_phi[wv][2 * NPTS + pos] = cd.y; } ++pos; }
        if (in2) { if (pos < NPTS) { s_phi[wv][pos] = ca.z; s_phi[wv][NPTS + pos] = cc.z; s_phi[wv][2 * NPTS + pos] = cd.z; } ++pos; }
        if (in3) { if (pos < NPTS) { s_phi[wv][pos] = ca.w; s_phi[wv][NPTS + pos] = cc.w; s_phi[wv][2 * NPTS + pos] = cd.w; } ++pos; }

        cnt += __popcll(m0) + __popcll(m1) + __popcll(m2) + __popcll(m3);
        if (cnt >= NPTS) break;  // wave-uniform exit
    }

    __syncthreads();  // all waves reach; makes scan LDS writes unambiguous

    const int n = (cnt < NPTS) ? cnt : NPTS;
    if (n == 0) {
        for (int j = lane; j < 3 * NPTS; j += 64) s_phi[wv][j] = 0.0f;
    } else if (n < NPTS) {
        // wrap: idx[j] = inside_idx[j % n]; reads [0,n) writes [n,NPTS) — disjoint
        for (int j = n + lane; j < NPTS; j += 64) {
            const int src = j % n;
            s_phi[wv][j]            = s_phi[wv][src];
            s_phi[wv][NPTS + j]     = s_phi[wv][NPTS + src];
            s_phi[wv][2 * NPTS + j] = s_phi[wv][2 * NPTS + src];
        }
    }
    __syncthreads();

    // transposed store: column b of phiT (L2 merges the 4B scatters)
    for (int i = lane; i < 3 * NPTS; i += 64)
        phiT[(size_t)i * B + b] = s_phi[wv][i];
}

// ---------------- Kernel A: h1 = relu(phi@W1^T+b1), lo = relu(l@W2^T+b2) ----
// lane = batch (all activation traffic coalesced); weights are wave-uniform
// scalar-cache broadcasts (readfirstlane-pinned base). Wave computes 16 k.
__global__ __launch_bounds__(256) void mlp1_kernel(
    const float* __restrict__ phiT,  // (300,B)
    const float* __restrict__ l,     // (B,3)
    const float* __restrict__ W1,    // (128,300)
    const float* __restrict__ b1,    // (128)
    const float* __restrict__ W2,    // (128,3)
    const float* __restrict__ b2,    // (128)
    float* __restrict__ h1T,         // (128,B)
    float* __restrict__ loT,         // (128,B)
    int B)
{
    const int tid  = threadIdx.x;
    const int wv   = tid >> 6;
    const int lane = tid & 63;
    const int BG   = B >> 6;
    const int bg   = blockIdx.x % BG;
    const int kh   = blockIdx.x / BG;        // 0 or 1
    const int col  = bg * 64 + lane;
    const int k0   = __builtin_amdgcn_readfirstlane(kh * 64 + wv * 16);

    float acc[16];
    #pragma unroll
    for (int kk = 0; kk < 16; ++kk) acc[kk] = b1[k0 + kk];

    const float* __restrict__ w1 = W1 + (size_t)k0 * 300;
    #pragma unroll 4
    for (int i = 0; i < 300; ++i) {
        const float pv = phiT[(size_t)i * B + col];   // coalesced 256B
        #pragma unroll
        for (int kk = 0; kk < 16; ++kk)
            acc[kk] = fmaf(pv, w1[kk * 300 + i], acc[kk]);  // uniform → s_load broadcast
    }
    #pragma unroll
    for (int kk = 0; kk < 16; ++kk)
        h1T[(size_t)(k0 + kk) * B + col] = fmaxf(acc[kk], 0.0f);  // coalesced

    const float l0 = l[col * 3 + 0];
    const float l1 = l[col * 3 + 1];
    const float l2 = l[col * 3 + 2];
    #pragma unroll
    for (int kk = 0; kk < 16; ++kk) {
        const int k = k0 + kk;
        const float lo = b2[k] + l0 * W2[k * 3 + 0] + l1 * W2[k * 3 + 1] + l2 * W2[k * 3 + 2];
        loT[(size_t)k * B + col] = fmaxf(lo, 0.0f);
    }
}

// ---------------- Kernel B: out = relu(h1@W3^T + lo@W4^T + b3 + b4) --------
// Same layout; LDS 64x65 tile transposes so the (B,256) output store is
// coalesced.
__global__ __launch_bounds__(256) void mlp2_kernel(
    const float* __restrict__ h1T,   // (128,B)
    const float* __restrict__ loT,   // (128,B)
    const float* __restrict__ W3,    // (256,128)
    const float* __restrict__ b3,    // (256)
    const float* __restrict__ W4,    // (256,128)
    const float* __restrict__ b4,    // (256)
    float* __restrict__ out,         // (B,256)
    int B)
{
    const int tid  = threadIdx.x;
    const int wv   = tid >> 6;
    const int lane = tid & 63;
    const int BG   = B >> 6;
    const int bg   = blockIdx.x % BG;
    const int mq   = blockIdx.x / BG;        // 0..3
    const int col  = bg * 64 + lane;
    const int m0   = __builtin_amdgcn_readfirstlane(mq * 64 + wv * 16);

    float acc[16];
    #pragma unroll
    for (int kk = 0; kk < 16; ++kk) acc[kk] = b3[m0 + kk] + b4[m0 + kk];

    const float* __restrict__ w3 = W3 + (size_t)m0 * 128;
    const float* __restrict__ w4 = W4 + (size_t)m0 * 128;
    #pragma unroll 2
    for (int k = 0; k < 128; ++k) {
        const float hv = h1T[(size_t)k * B + col];    // coalesced
        const float lv = loT[(size_t)k * B + col];    // coalesced
        #pragma unroll
        for (int kk = 0; kk < 16; ++kk)
            acc[kk] = fmaf(hv, w3[kk * 128 + k], fmaf(lv, w4[kk * 128 + k], acc[kk]));
    }

    __shared__ float s_o[64][65];   // +1 pad: transpose reads conflict-free
    #pragma unroll
    for (int kk = 0; kk < 16; ++kk)
        s_o[wv * 16 + kk][lane] = fmaxf(acc[kk], 0.0f);
    __syncthreads();
    #pragma unroll
    for (int r = 0; r < 16; ++r) {
        const int bb = wv * 16 + r;
        out[(size_t)(bg * 64 + bb) * 256 + mq * 64 + lane] = s_o[lane][bb];  // coalesced
    }
}

extern "C" void kernel_launch(void* const* d_in, const int* in_sizes, int n_in,
                              void* d_out, int out_size, void* d_ws, size_t ws_size,
                              hipStream_t stream) {
    const float* x  = (const float*)d_in[0];
    const float* l  = (const float*)d_in[1];
    const float* W1 = (const float*)d_in[2];
    const float* b1 = (const float*)d_in[3];
    const float* W2 = (const float*)d_in[4];
    const float* b2 = (const float*)d_in[5];
    const float* W3 = (const float*)d_in[6];
    const float* b3 = (const float*)d_in[7];
    const float* W4 = (const float*)d_in[8];
    const float* b4 = (const float*)d_in[9];
    float* out = (float*)d_out;

    const int B = in_sizes[1] / 3;  // 4096

    float* phiT = (float*)d_ws;            // 300*B floats = 4.9 MB
    float* h1T  = phiT + (size_t)300 * B;  // 128*B floats = 2.0 MB
    float* loT  = h1T  + (size_t)128 * B;  // 128*B floats = 2.0 MB

    foveate_kernel<<<B / 4, 256, 0, stream>>>(x, l, phiT, B);
    mlp1_kernel<<<2 * (B / 64), 256, 0, stream>>>(phiT, l, W1, b1, W2, b2, h1T, loT, B);
    mlp2_kernel<<<4 * (B / 64), 256, 0, stream>>>(h1T, loT, W3, b3, W4, b4, out, B);
}